// Round 8
// baseline (1316.028 us; speedup 1.0000x reference)
//
#include <hip/hip_runtime.h>

#define HID 64
#define IN_DIM 34
#define NCLS 10
#define BLK 128   // edge kernel block size: the ONLY config with clean VGPR alloc (R4)
#define TSTR 35   // LDS tile row stride; odd -> conflict-free column reads

// ---------- helpers ----------

__device__ __forceinline__ unsigned enc_f(float f) {
    unsigned u = __float_as_uint(f);
    return (u & 0x80000000u) ? ~u : (u | 0x80000000u);
}
__device__ __forceinline__ float dec_f(unsigned u) {
    return __uint_as_float((u & 0x80000000u) ? (u & 0x7FFFFFFFu) : ~u);
}

// 34 -> 64 (relu) -> 64 MLP, register-blocked. Weight indices wave-uniform
// -> scalar loads.
__device__ __forceinline__ void mlp34_64(const float (&ea)[IN_DIM],
        const float* __restrict__ W1, const float* __restrict__ b1,
        const float* __restrict__ W2, const float* __restrict__ b2,
        float (&out)[HID]) {
    #pragma unroll
    for (int j = 0; j < HID; ++j) out[j] = b2[j];
    #pragma unroll 1
    for (int jb = 0; jb < HID; jb += 8) {
        float hb[8];
        #pragma unroll
        for (int u = 0; u < 8; ++u) hb[u] = b1[jb + u];
        #pragma unroll
        for (int k = 0; k < IN_DIM; ++k) {
            #pragma unroll
            for (int u = 0; u < 8; ++u)
                hb[u] = fmaf(ea[k], W1[k * HID + jb + u], hb[u]);
        }
        #pragma unroll
        for (int u = 0; u < 8; ++u) hb[u] = fmaxf(hb[u], 0.0f);
        #pragma unroll
        for (int u = 0; u < 8; ++u) {
            float hv = hb[u];
            #pragma unroll
            for (int j = 0; j < HID; ++j)
                out[j] = fmaf(hv, W2[(jb + u) * HID + j], out[j]);
        }
    }
}

// ---------- CSR build ----------

__global__ __launch_bounds__(256) void hist_pass(
        const int* __restrict__ ei, int* __restrict__ hist, int E) {
    int e = blockIdx.x * blockDim.x + threadIdx.x;
    if (e >= E) return;
    atomicAdd(&hist[ei[E + e]], 1);
}

__global__ __launch_bounds__(256) void scan1(
        const int* __restrict__ hist, int* __restrict__ loc,
        int* __restrict__ part, int N) {
    __shared__ int sh[256];
    int tid = threadIdx.x;
    int i = blockIdx.x * 256 + tid;
    int v = (i < N) ? hist[i] : 0;
    sh[tid] = v;
    __syncthreads();
    for (int d = 1; d < 256; d <<= 1) {
        int t = (tid >= d) ? sh[tid - d] : 0;
        __syncthreads();
        sh[tid] += t;
        __syncthreads();
    }
    if (i < N) loc[i] = sh[tid] - v;          // exclusive
    if (tid == 255) part[blockIdx.x] = sh[255];
}

__global__ __launch_bounds__(512) void scan2(int* __restrict__ part, int NB) {
    __shared__ int sh[512];
    int t = threadIdx.x;
    int v = (t < NB) ? part[t] : 0;
    sh[t] = v;
    __syncthreads();
    for (int d = 1; d < 512; d <<= 1) {
        int u = (t >= d) ? sh[t - d] : 0;
        __syncthreads();
        sh[t] += u;
        __syncthreads();
    }
    if (t < NB) part[t] = sh[t] - v;          // exclusive
}

__global__ __launch_bounds__(256) void scan3(
        const int* __restrict__ loc, const int* __restrict__ part,
        int* __restrict__ offs, int* __restrict__ cursor, int N) {
    int i = blockIdx.x * 256 + threadIdx.x;
    if (i >= N) return;
    int o = loc[i] + part[blockIdx.x];
    offs[i] = o;
    cursor[i] = o;
}

// bucket edges by col; pre-gather packed (port | flag<<16).
__global__ __launch_bounds__(256) void sort_pass(
        const int* __restrict__ ei, const int* __restrict__ ports,
        const int* __restrict__ flags, int* __restrict__ cursor,
        int* __restrict__ eid_sorted, int* __restrict__ src_sorted,
        int* __restrict__ col_sorted, unsigned* __restrict__ pf_sorted, int E) {
    int e = blockIdx.x * blockDim.x + threadIdx.x;
    if (e >= E) return;
    int c = ei[E + e];
    int pos = atomicAdd(&cursor[c], 1);
    eid_sorted[pos] = e;
    src_sorted[pos] = ei[e];
    col_sorted[pos] = c;
    pf_sorted[pos] = (unsigned)ports[e] | ((unsigned)flags[e] << 16);
}

// ---------- edge-parallel MLP + block segmented reduction ----------
// 128 threads/block (2 waves), thread per sorted edge. R4 proved this block
// size gets a clean ~90-VGPR allocation (no AGPR parking, no spill); the R4
// occupancy limiter (33 KB LDS) is fixed by staging through a 128x35 tile in
// 32-column half passes: 18.4 KB -> 8 blocks/CU = 16 waves/CU.
// NO launch-bounds minimum: every attempt to force one (R5/R7) caused the
// allocator to spill the whole live set to scratch (FETCH 170->700 MB).
__global__ __launch_bounds__(BLK) void edge_mlp_reduce(
        const int* __restrict__ eid_sorted, const int* __restrict__ col_sorted,
        const unsigned* __restrict__ pf_sorted, const float* __restrict__ eattr,
        const float* __restrict__ emb_port, const float* __restrict__ emb_flags,
        const float* __restrict__ W1, const float* __restrict__ b1,
        const float* __restrict__ W2, const float* __restrict__ b2,
        float* __restrict__ s, float* __restrict__ lsum, int E) {
    __shared__ float tile[BLK * TSTR];
    __shared__ int col_sh[BLK];

    int tid = threadIdx.x;
    int lane = tid & 63;
    int wv = tid >> 6;
    int idx = blockIdx.x * BLK + tid;
    bool valid = idx < E;

    col_sh[tid] = valid ? col_sorted[idx] : -1;

    // ---- gather ea[34] ----
    float ea[IN_DIM];
    #pragma unroll
    for (int k = 0; k < IN_DIM; ++k) ea[k] = 0.0f;
    if (valid) {
        int eid = eid_sorted[idx];
        const float4* ap = (const float4*)(eattr + (size_t)eid * 16);
        float4 a0 = ap[0], a1 = ap[1], a2 = ap[2], a3 = ap[3];
        ea[0]=a0.x; ea[1]=a0.y; ea[2]=a0.z; ea[3]=a0.w;
        ea[4]=a1.x; ea[5]=a1.y; ea[6]=a1.z; ea[7]=a1.w;
        ea[8]=a2.x; ea[9]=a2.y; ea[10]=a2.z; ea[11]=a2.w;
        ea[12]=a3.x; ea[13]=a3.y; ea[14]=a3.z; ea[15]=a3.w;
        unsigned pf = pf_sorted[idx];
        int p = (int)(pf & 0xFFFFu);
        int f = (int)(pf >> 16);
        const float4* pp = (const float4*)(emb_port + (size_t)p * 16);
        float4 p0 = pp[0], p1 = pp[1], p2 = pp[2], p3 = pp[3];
        ea[16]=p0.x; ea[17]=p0.y; ea[18]=p0.z; ea[19]=p0.w;
        ea[20]=p1.x; ea[21]=p1.y; ea[22]=p1.z; ea[23]=p1.w;
        ea[24]=p2.x; ea[25]=p2.y; ea[26]=p2.z; ea[27]=p2.w;
        ea[28]=p3.x; ea[29]=p3.y; ea[30]=p3.z; ea[31]=p3.w;
        float2 fl = *(const float2*)(emb_flags + (size_t)f * 2);
        ea[32]=fl.x; ea[33]=fl.y;
    }

    __syncthreads();   // col_sh visible

    // ---- phase 1: lsum (34 raw channels); only ea[34] live across it ----
    #pragma unroll
    for (int k = 0; k < IN_DIM; ++k) tile[tid * TSTR + k] = ea[k];
    __syncthreads();
    {
        int cj = (lane < IN_DIM) ? lane : IN_DIM;   // col 34 = in-stride dummy
        int r0 = wv * 64;
        float acc = 0.0f;
        int cur = col_sh[r0];
        #pragma unroll 1
        for (int rb = 0; rb < 64; rb += 8) {
            float v[8];
            #pragma unroll
            for (int u = 0; u < 8; ++u)
                v[u] = tile[(r0 + rb + u) * TSTR + cj];
            #pragma unroll
            for (int u = 0; u < 8; ++u) {
                int cr = col_sh[r0 + rb + u];
                if (cr != cur) {
                    if (cur >= 0 && lane < IN_DIM)
                        atomicAdd(&lsum[(size_t)cur * IN_DIM + lane], acc);
                    acc = 0.0f;
                    cur = cr;
                }
                acc += v[u];
            }
        }
        if (cur >= 0 && lane < IN_DIM)
            atomicAdd(&lsum[(size_t)cur * IN_DIM + lane], acc);
    }
    __syncthreads();

    // ---- MLP (single pass, R4-style): ea dies, out[64] born ----
    float out[HID];
    mlp34_64(ea, W1, b1, W2, b2, out);

    // ---- phases 2-3: stage/reduce out in 32-column halves ----
    #pragma unroll 1
    for (int half = 0; half < 2; ++half) {
        int cbase = half * 32;
        #pragma unroll
        for (int j = 0; j < 32; ++j) tile[tid * TSTR + j] = out[cbase + j];
        __syncthreads();

        // lane-half owns a 32-row strip, lane&31 owns one column
        int colL = lane & 31;
        int r0 = wv * 64 + (lane >> 5) * 32;
        float acc = 0.0f;
        int cur = col_sh[r0];
        #pragma unroll 1
        for (int rb = 0; rb < 32; rb += 8) {
            float v[8];
            #pragma unroll
            for (int u = 0; u < 8; ++u)
                v[u] = tile[(r0 + rb + u) * TSTR + colL];
            #pragma unroll
            for (int u = 0; u < 8; ++u) {
                int cr = col_sh[r0 + rb + u];
                if (cr != cur) {
                    if (cur >= 0)
                        atomicAdd(&s[(size_t)cur * HID + cbase + colL], acc);
                    acc = 0.0f;
                    cur = cr;
                }
                acc += v[u];
            }
        }
        if (cur >= 0)
            atomicAdd(&s[(size_t)cur * HID + cbase + colL], acc);
        __syncthreads();
    }
}

// Thread per node: self-loop MLP, finalize s, write x1 = s/deg.
__global__ __launch_bounds__(256) void node_mlp(
        const float* __restrict__ lsum, const int* __restrict__ hist,
        const float* __restrict__ W1, const float* __restrict__ b1,
        const float* __restrict__ W2, const float* __restrict__ b2,
        float* __restrict__ s, float* __restrict__ x1, int N) {
    int n = blockIdx.x * blockDim.x + threadIdx.x;
    if (n >= N) return;
    int c = hist[n];
    float invc = 1.0f / fmaxf((float)c, 1.0f);
    float ea[IN_DIM];
    const float* lp = lsum + (size_t)n * IN_DIM;
    #pragma unroll
    for (int k = 0; k < IN_DIM; ++k) ea[k] = lp[k] * invc;
    float out[HID];
    mlp34_64(ea, W1, b1, W2, b2, out);
    float invdeg = 1.0f / (float)(c + 1);
    float* sp = s + (size_t)n * HID;
    float* xp = x1 + (size_t)n * HID;
    #pragma unroll
    for (int j = 0; j < HID; ++j) {
        float t = sp[j] + out[j];
        sp[j] = t;
        xp[j] = t * invdeg;
    }
}

// Wave per node, 8-wide pipelined gather:
// xn[n] = (sum_{incoming} x[src] + x[n] + s[n]) / deg
__global__ __launch_bounds__(256) void gather_layer(
        const int* __restrict__ offs, const int* __restrict__ hist,
        const int* __restrict__ src_sorted, const float* __restrict__ x,
        const float* __restrict__ s, float* __restrict__ xn, int N) {
    int wid = (blockIdx.x * blockDim.x + threadIdx.x) >> 6;
    int lane = threadIdx.x & 63;
    if (wid >= N) return;
    int off = offs[wid], d = hist[wid];
    float acc = x[(size_t)wid * HID + lane] + s[(size_t)wid * HID + lane];
    int i = 0;
    for (; i + 8 <= d; i += 8) {
        int r[8];
        #pragma unroll
        for (int u = 0; u < 8; ++u) r[u] = src_sorted[off + i + u];
        float v[8];
        #pragma unroll
        for (int u = 0; u < 8; ++u) v[u] = x[(size_t)r[u] * HID + lane];
        #pragma unroll
        for (int u = 0; u < 8; ++u) acc += v[u];
    }
    for (; i < d; ++i) {
        int r = src_sorted[off + i];
        acc += x[(size_t)r * HID + lane];
    }
    xn[(size_t)wid * HID + lane] = acc / (float)(d + 1);
}

// Wave per 64-node chunk; batch[] is sorted so flushes are rare.
__global__ __launch_bounds__(256) void pool_pass(
        const float* __restrict__ x, const int* __restrict__ batch,
        float* __restrict__ psum, unsigned* __restrict__ pmax,
        float* __restrict__ pcnt, int N) {
    const int CHUNK = 64;
    int wid = (blockIdx.x * blockDim.x + threadIdx.x) >> 6;
    int lane = threadIdx.x & 63;
    int n0 = wid * CHUNK;
    if (n0 >= N) return;
    int n1 = min(n0 + CHUNK, N);
    int gcur = batch[n0];
    float sum = 0.0f, mx = -3.402823e38f;
    int cnt = 0;
    for (int n = n0; n < n1; ++n) {
        int g = batch[n];
        if (g != gcur) {
            atomicAdd(&psum[gcur * HID + lane], sum);
            atomicMax(&pmax[gcur * HID + lane], enc_f(mx));
            if (lane == 0) atomicAdd(&pcnt[gcur], (float)cnt);
            gcur = g; sum = 0.0f; mx = -3.402823e38f; cnt = 0;
        }
        float v = x[(size_t)n * HID + lane];
        sum += v;
        mx = fmaxf(mx, v);
        ++cnt;
    }
    atomicAdd(&psum[gcur * HID + lane], sum);
    atomicMax(&pmax[gcur * HID + lane], enc_f(mx));
    if (lane == 0) atomicAdd(&pcnt[gcur], (float)cnt);
}

__global__ __launch_bounds__(64) void classifier_pass(
        const float* __restrict__ psum, const unsigned* __restrict__ pmax,
        const float* __restrict__ pcnt,
        const float* __restrict__ CW1, const float* __restrict__ Cb1,
        const float* __restrict__ CW2, const float* __restrict__ Cb2,
        float* __restrict__ out) {
    int g = blockIdx.x, j = threadIdx.x;
    __shared__ float pooled[2 * HID];
    __shared__ float hsh[HID];
    float gc = fmaxf(pcnt[g], 1.0f);
    pooled[j] = psum[g * HID + j] / gc;
    pooled[HID + j] = dec_f(pmax[g * HID + j]);
    __syncthreads();
    float acc = Cb1[j];
    #pragma unroll 8
    for (int k = 0; k < 2 * HID; ++k) acc = fmaf(pooled[k], CW1[k * HID + j], acc);
    hsh[j] = fmaxf(acc, 0.0f);
    __syncthreads();
    if (j < NCLS) {
        float o = Cb2[j];
        #pragma unroll 8
        for (int k = 0; k < HID; ++k) o = fmaf(hsh[k], CW2[k * NCLS + j], o);
        out[g * NCLS + j] = o;
    }
}

// ---------- launch ----------

extern "C" void kernel_launch(void* const* d_in, const int* in_sizes, int n_in,
                              void* d_out, int out_size, void* d_ws, size_t ws_size,
                              hipStream_t stream) {
    const int*   ei        = (const int*)d_in[0];
    const int*   ports     = (const int*)d_in[1];
    const int*   flags     = (const int*)d_in[2];
    const float* eattr     = (const float*)d_in[3];
    const int*   batch     = (const int*)d_in[4];
    const float* emb_port  = (const float*)d_in[5];
    const float* emb_flags = (const float*)d_in[6];
    const float* W1  = (const float*)d_in[7];
    const float* b1  = (const float*)d_in[8];
    const float* W2  = (const float*)d_in[9];
    const float* b2  = (const float*)d_in[10];
    const float* CW1 = (const float*)d_in[11];
    const float* Cb1 = (const float*)d_in[12];
    const float* CW2 = (const float*)d_in[13];
    const float* Cb2 = (const float*)d_in[14];
    float* outp = (float*)d_out;

    const int E = in_sizes[0] / 2;
    const int N = in_sizes[4];
    const int B = out_size / NCLS;
    const int NB = (N + 255) / 256;     // scan blocks (must be <= 512)

    // ---- workspace layout (~118 MB; proven-safe budget >= 142 MB) ----
    char* w = (char*)d_ws;
    float*    xA         = (float*)w;   w += (size_t)N * HID * 4;
    float*    xB         = (float*)w;   w += (size_t)N * HID * 4;
    int*      eid_sorted = (int*)w;     w += (size_t)E * 4;
    int*      src_sorted = (int*)w;     w += (size_t)E * 4;
    int*      col_sorted = (int*)w;     w += (size_t)E * 4;
    unsigned* pf_sorted  = (unsigned*)w; w += (size_t)E * 4;
    int*      offs       = (int*)w;     w += (size_t)N * 4;
    int*      cursor     = (int*)w;     w += (size_t)N * 4;
    int*      loc        = (int*)w;     w += (size_t)N * 4;
    int*      part       = (int*)w;     w += 512 * 4;
    // zero region (single memset): hist, s, lsum, psum, pmax, pcnt
    char* zero_base = w;
    int*      hist  = (int*)w;          w += (size_t)N * 4;
    float*    s     = (float*)w;        w += (size_t)N * HID * 4;
    float*    lsum  = (float*)w;        w += (size_t)N * IN_DIM * 4;
    float*    psum  = (float*)w;        w += (size_t)B * HID * 4;
    unsigned* pmax  = (unsigned*)w;     w += (size_t)B * HID * 4;
    float*    pcnt  = (float*)w;        w += (size_t)B * 4;
    size_t zero_bytes = (size_t)(w - zero_base);

    hipMemsetAsync(zero_base, 0, zero_bytes, stream);

    // CSR build + bucket sort by col
    hist_pass<<<(E + 255) / 256, 256, 0, stream>>>(ei, hist, E);
    scan1<<<NB, 256, 0, stream>>>(hist, loc, part, N);
    scan2<<<1, 512, 0, stream>>>(part, NB);
    scan3<<<NB, 256, 0, stream>>>(loc, part, offs, cursor, N);
    sort_pass<<<(E + 255) / 256, 256, 0, stream>>>(
        ei, ports, flags, cursor, eid_sorted, src_sorted, col_sorted, pf_sorted, E);

    // edge-parallel MLP + segmented reduction -> s, lsum
    edge_mlp_reduce<<<(E + BLK - 1) / BLK, BLK, 0, stream>>>(
        eid_sorted, col_sorted, pf_sorted, eattr, emb_port, emb_flags,
        W1, b1, W2, b2, s, lsum, E);

    // self-loop MLP, finalize -> x1
    node_mlp<<<(N + 255) / 256, 256, 0, stream>>>(
        lsum, hist, W1, b1, W2, b2, s, xA, N);

    // layers 2 and 3
    gather_layer<<<(N + 3) / 4, 256, 0, stream>>>(
        offs, hist, src_sorted, xA, s, xB, N);
    gather_layer<<<(N + 3) / 4, 256, 0, stream>>>(
        offs, hist, src_sorted, xB, s, xA, N);

    // pooling + classifier
    pool_pass<<<((N + 63) / 64 * 64 + 255) / 256, 256, 0, stream>>>(
        xA, batch, psum, pmax, pcnt, N);
    classifier_pass<<<B, 64, 0, stream>>>(psum, pmax, pcnt, CW1, Cb1, CW2, Cb2, outp);
}

// Round 9
// 951.628 us; speedup vs baseline: 1.3829x; 1.3829x over previous
//
#include <hip/hip_runtime.h>

#define HID 64
#define IN_DIM 34
#define NCLS 10
#define BLK 128   // edge kernel block size: proven-clean VGPR alloc (R4/R8)
#define TSTR 35   // LDS tile row stride; odd -> conflict-free column reads

// ---------- helpers ----------

__device__ __forceinline__ unsigned enc_f(float f) {
    unsigned u = __float_as_uint(f);
    return (u & 0x80000000u) ? ~u : (u | 0x80000000u);
}
__device__ __forceinline__ float dec_f(unsigned u) {
    return __uint_as_float((u & 0x80000000u) ? (u & 0x7FFFFFFFu) : ~u);
}

// ---------- CSR build ----------

__global__ __launch_bounds__(256) void hist_pass(
        const int* __restrict__ ei, int* __restrict__ hist, int E) {
    int e = blockIdx.x * blockDim.x + threadIdx.x;
    if (e >= E) return;
    atomicAdd(&hist[ei[E + e]], 1);
}

__global__ __launch_bounds__(256) void scan1(
        const int* __restrict__ hist, int* __restrict__ loc,
        int* __restrict__ part, int N) {
    __shared__ int sh[256];
    int tid = threadIdx.x;
    int i = blockIdx.x * 256 + tid;
    int v = (i < N) ? hist[i] : 0;
    sh[tid] = v;
    __syncthreads();
    for (int d = 1; d < 256; d <<= 1) {
        int t = (tid >= d) ? sh[tid - d] : 0;
        __syncthreads();
        sh[tid] += t;
        __syncthreads();
    }
    if (i < N) loc[i] = sh[tid] - v;          // exclusive
    if (tid == 255) part[blockIdx.x] = sh[255];
}

__global__ __launch_bounds__(512) void scan2(int* __restrict__ part, int NB) {
    __shared__ int sh[512];
    int t = threadIdx.x;
    int v = (t < NB) ? part[t] : 0;
    sh[t] = v;
    __syncthreads();
    for (int d = 1; d < 512; d <<= 1) {
        int u = (t >= d) ? sh[t - d] : 0;
        __syncthreads();
        sh[t] += u;
        __syncthreads();
    }
    if (t < NB) part[t] = sh[t] - v;          // exclusive
}

__global__ __launch_bounds__(256) void scan3(
        const int* __restrict__ loc, const int* __restrict__ part,
        int* __restrict__ offs, int* __restrict__ cursor, int N) {
    int i = blockIdx.x * 256 + threadIdx.x;
    if (i >= N) return;
    int o = loc[i] + part[blockIdx.x];
    offs[i] = o;
    cursor[i] = o;
}

// bucket edges by col; pre-gather packed (port | flag<<16).
__global__ __launch_bounds__(256) void sort_pass(
        const int* __restrict__ ei, const int* __restrict__ ports,
        const int* __restrict__ flags, int* __restrict__ cursor,
        int* __restrict__ eid_sorted, int* __restrict__ src_sorted,
        int* __restrict__ col_sorted, unsigned* __restrict__ pf_sorted, int E) {
    int e = blockIdx.x * blockDim.x + threadIdx.x;
    if (e >= E) return;
    int c = ei[E + e];
    int pos = atomicAdd(&cursor[c], 1);
    eid_sorted[pos] = e;
    src_sorted[pos] = ei[e];
    col_sorted[pos] = c;
    pf_sorted[pos] = (unsigned)ports[e] | ((unsigned)flags[e] << 16);
}

// ---------- edge hidden-layer + block segmented reduction ----------
// ALGEBRAIC KEY: s[n] = (sum_e relu(ea_e W1 + b1) + h_loop) W2 + (d+1) b2.
// Only the HIDDEN layer is per-edge (2176 FMA, 3x less than full MLP);
// the W2 matmul is deferred to node_mlp (per node, trivial).
// Register discipline (R4/R6/R8 lessons): the only array live across a
// barrier is ea[34]; each h[32] half is staged to LDS and dies immediately.
// 128 threads, 18.4 KB LDS -> 8 blocks/CU; no launch-bounds minimum.
__global__ __launch_bounds__(BLK) void edge_hidden_reduce(
        const int* __restrict__ eid_sorted, const int* __restrict__ col_sorted,
        const unsigned* __restrict__ pf_sorted, const float* __restrict__ eattr,
        const float* __restrict__ emb_port, const float* __restrict__ emb_flags,
        const float* __restrict__ W1, const float* __restrict__ b1,
        float* __restrict__ hsum, float* __restrict__ lsum, int E) {
    __shared__ float tile[BLK * TSTR];
    __shared__ int col_sh[BLK];

    int tid = threadIdx.x;
    int lane = tid & 63;
    int wv = tid >> 6;
    int idx = blockIdx.x * BLK + tid;
    bool valid = idx < E;

    col_sh[tid] = valid ? col_sorted[idx] : -1;

    // ---- gather ea[34] ----
    float ea[IN_DIM];
    #pragma unroll
    for (int k = 0; k < IN_DIM; ++k) ea[k] = 0.0f;
    if (valid) {
        int eid = eid_sorted[idx];
        const float4* ap = (const float4*)(eattr + (size_t)eid * 16);
        float4 a0 = ap[0], a1 = ap[1], a2 = ap[2], a3 = ap[3];
        ea[0]=a0.x; ea[1]=a0.y; ea[2]=a0.z; ea[3]=a0.w;
        ea[4]=a1.x; ea[5]=a1.y; ea[6]=a1.z; ea[7]=a1.w;
        ea[8]=a2.x; ea[9]=a2.y; ea[10]=a2.z; ea[11]=a2.w;
        ea[12]=a3.x; ea[13]=a3.y; ea[14]=a3.z; ea[15]=a3.w;
        unsigned pf = pf_sorted[idx];
        int p = (int)(pf & 0xFFFFu);
        int f = (int)(pf >> 16);
        const float4* pp = (const float4*)(emb_port + (size_t)p * 16);
        float4 p0 = pp[0], p1 = pp[1], p2 = pp[2], p3 = pp[3];
        ea[16]=p0.x; ea[17]=p0.y; ea[18]=p0.z; ea[19]=p0.w;
        ea[20]=p1.x; ea[21]=p1.y; ea[22]=p1.z; ea[23]=p1.w;
        ea[24]=p2.x; ea[25]=p2.y; ea[26]=p2.z; ea[27]=p2.w;
        ea[28]=p3.x; ea[29]=p3.y; ea[30]=p3.z; ea[31]=p3.w;
        float2 fl = *(const float2*)(emb_flags + (size_t)f * 2);
        ea[32]=fl.x; ea[33]=fl.y;
    }

    __syncthreads();   // col_sh visible

    // ---- phase 1: lsum (34 raw channels) ----
    #pragma unroll
    for (int k = 0; k < IN_DIM; ++k) tile[tid * TSTR + k] = ea[k];
    __syncthreads();
    {
        int cj = (lane < IN_DIM) ? lane : IN_DIM;   // col 34 = in-stride dummy
        int r0 = wv * 64;
        float acc = 0.0f;
        int cur = col_sh[r0];
        #pragma unroll 1
        for (int rb = 0; rb < 64; rb += 8) {
            float v[8];
            #pragma unroll
            for (int u = 0; u < 8; ++u)
                v[u] = tile[(r0 + rb + u) * TSTR + cj];
            #pragma unroll
            for (int u = 0; u < 8; ++u) {
                int cr = col_sh[r0 + rb + u];
                if (cr != cur) {
                    if (cur >= 0 && lane < IN_DIM)
                        atomicAdd(&lsum[(size_t)cur * IN_DIM + lane], acc);
                    acc = 0.0f;
                    cur = cr;
                }
                acc += v[u];
            }
        }
        if (cur >= 0 && lane < IN_DIM)
            atomicAdd(&lsum[(size_t)cur * IN_DIM + lane], acc);
    }
    __syncthreads();

    // ---- phases 2-3: hidden halves h[32] = relu(ea @ W1half + b1half) ----
    #pragma unroll 1
    for (int half = 0; half < 2; ++half) {
        int cbase = half * 32;
        float h[32];
        #pragma unroll
        for (int j = 0; j < 32; ++j) h[j] = b1[cbase + j];
        #pragma unroll 2
        for (int k = 0; k < IN_DIM; ++k) {
            float v = ea[k];
            #pragma unroll
            for (int j = 0; j < 32; ++j)
                h[j] = fmaf(v, W1[k * HID + cbase + j], h[j]);
        }
        // stage (h dies here -> nothing wide crosses the barrier)
        #pragma unroll
        for (int j = 0; j < 32; ++j)
            tile[tid * TSTR + j] = fmaxf(h[j], 0.0f);
        __syncthreads();

        // reduce: lane-half owns a 32-row strip, lane&31 owns one column
        int colL = lane & 31;
        int r0 = wv * 64 + (lane >> 5) * 32;
        float acc = 0.0f;
        int cur = col_sh[r0];
        #pragma unroll 1
        for (int rb = 0; rb < 32; rb += 8) {
            float v[8];
            #pragma unroll
            for (int u = 0; u < 8; ++u)
                v[u] = tile[(r0 + rb + u) * TSTR + colL];
            #pragma unroll
            for (int u = 0; u < 8; ++u) {
                int cr = col_sh[r0 + rb + u];
                if (cr != cur) {
                    if (cur >= 0)
                        atomicAdd(&hsum[(size_t)cur * HID + cbase + colL], acc);
                    acc = 0.0f;
                    cur = cr;
                }
                acc += v[u];
            }
        }
        if (cur >= 0)
            atomicAdd(&hsum[(size_t)cur * HID + cbase + colL], acc);
        __syncthreads();
    }
}

// Thread per node: self-loop hidden, add hsum, apply W2 once per node.
// s[n] = (hsum[n] + relu(lsum/c W1 + b1)) W2 + (d+1) b2 ; x1 = s / (d+1)
__global__ __launch_bounds__(256) void node_mlp(
        const float* __restrict__ lsum, const float* __restrict__ hsum,
        const int* __restrict__ hist,
        const float* __restrict__ W1, const float* __restrict__ b1,
        const float* __restrict__ W2, const float* __restrict__ b2,
        float* __restrict__ s, float* __restrict__ x1, int N) {
    int n = blockIdx.x * blockDim.x + threadIdx.x;
    if (n >= N) return;
    int c = hist[n];
    float invc = 1.0f / fmaxf((float)c, 1.0f);

    // hs = relu(ea W1 + b1) + hsum[n]
    float hs[HID];
    #pragma unroll
    for (int j = 0; j < HID; ++j) hs[j] = b1[j];
    #pragma unroll 1
    for (int k = 0; k < IN_DIM; ++k) {
        float v = lsum[(size_t)n * IN_DIM + k] * invc;
        #pragma unroll
        for (int j = 0; j < HID; ++j)
            hs[j] = fmaf(v, W1[k * HID + j], hs[j]);
    }
    const float* hp = hsum + (size_t)n * HID;
    #pragma unroll
    for (int j = 0; j < HID; ++j) hs[j] = fmaxf(hs[j], 0.0f) + hp[j];

    float degf = (float)(c + 1);
    float invdeg = 1.0f / degf;
    float* sp = s + (size_t)n * HID;
    float* xp = x1 + (size_t)n * HID;
    #pragma unroll 1
    for (int jb = 0; jb < HID; jb += 8) {
        float o[8];
        #pragma unroll
        for (int u = 0; u < 8; ++u) o[u] = degf * b2[jb + u];
        #pragma unroll 2
        for (int k = 0; k < HID; ++k) {
            float hv = hs[k];
            #pragma unroll
            for (int u = 0; u < 8; ++u)
                o[u] = fmaf(hv, W2[k * HID + jb + u], o[u]);
        }
        #pragma unroll
        for (int u = 0; u < 8; ++u) {
            sp[jb + u] = o[u];
            xp[jb + u] = o[u] * invdeg;
        }
    }
}

// Wave per node, 8-wide pipelined gather:
// xn[n] = (sum_{incoming} x[src] + x[n] + s[n]) / deg
__global__ __launch_bounds__(256) void gather_layer(
        const int* __restrict__ offs, const int* __restrict__ hist,
        const int* __restrict__ src_sorted, const float* __restrict__ x,
        const float* __restrict__ s, float* __restrict__ xn, int N) {
    int wid = (blockIdx.x * blockDim.x + threadIdx.x) >> 6;
    int lane = threadIdx.x & 63;
    if (wid >= N) return;
    int off = offs[wid], d = hist[wid];
    float acc = x[(size_t)wid * HID + lane] + s[(size_t)wid * HID + lane];
    int i = 0;
    for (; i + 8 <= d; i += 8) {
        int r[8];
        #pragma unroll
        for (int u = 0; u < 8; ++u) r[u] = src_sorted[off + i + u];
        float v[8];
        #pragma unroll
        for (int u = 0; u < 8; ++u) v[u] = x[(size_t)r[u] * HID + lane];
        #pragma unroll
        for (int u = 0; u < 8; ++u) acc += v[u];
    }
    for (; i < d; ++i) {
        int r = src_sorted[off + i];
        acc += x[(size_t)r * HID + lane];
    }
    xn[(size_t)wid * HID + lane] = acc / (float)(d + 1);
}

// Wave per 64-node chunk; batch[] is sorted so flushes are rare.
__global__ __launch_bounds__(256) void pool_pass(
        const float* __restrict__ x, const int* __restrict__ batch,
        float* __restrict__ psum, unsigned* __restrict__ pmax,
        float* __restrict__ pcnt, int N) {
    const int CHUNK = 64;
    int wid = (blockIdx.x * blockDim.x + threadIdx.x) >> 6;
    int lane = threadIdx.x & 63;
    int n0 = wid * CHUNK;
    if (n0 >= N) return;
    int n1 = min(n0 + CHUNK, N);
    int gcur = batch[n0];
    float sum = 0.0f, mx = -3.402823e38f;
    int cnt = 0;
    for (int n = n0; n < n1; ++n) {
        int g = batch[n];
        if (g != gcur) {
            atomicAdd(&psum[gcur * HID + lane], sum);
            atomicMax(&pmax[gcur * HID + lane], enc_f(mx));
            if (lane == 0) atomicAdd(&pcnt[gcur], (float)cnt);
            gcur = g; sum = 0.0f; mx = -3.402823e38f; cnt = 0;
        }
        float v = x[(size_t)n * HID + lane];
        sum += v;
        mx = fmaxf(mx, v);
        ++cnt;
    }
    atomicAdd(&psum[gcur * HID + lane], sum);
    atomicMax(&pmax[gcur * HID + lane], enc_f(mx));
    if (lane == 0) atomicAdd(&pcnt[gcur], (float)cnt);
}

__global__ __launch_bounds__(64) void classifier_pass(
        const float* __restrict__ psum, const unsigned* __restrict__ pmax,
        const float* __restrict__ pcnt,
        const float* __restrict__ CW1, const float* __restrict__ Cb1,
        const float* __restrict__ CW2, const float* __restrict__ Cb2,
        float* __restrict__ out) {
    int g = blockIdx.x, j = threadIdx.x;
    __shared__ float pooled[2 * HID];
    __shared__ float hsh[HID];
    float gc = fmaxf(pcnt[g], 1.0f);
    pooled[j] = psum[g * HID + j] / gc;
    pooled[HID + j] = dec_f(pmax[g * HID + j]);
    __syncthreads();
    float acc = Cb1[j];
    #pragma unroll 8
    for (int k = 0; k < 2 * HID; ++k) acc = fmaf(pooled[k], CW1[k * HID + j], acc);
    hsh[j] = fmaxf(acc, 0.0f);
    __syncthreads();
    if (j < NCLS) {
        float o = Cb2[j];
        #pragma unroll 8
        for (int k = 0; k < HID; ++k) o = fmaf(hsh[k], CW2[k * NCLS + j], o);
        out[g * NCLS + j] = o;
    }
}

// ---------- launch ----------

extern "C" void kernel_launch(void* const* d_in, const int* in_sizes, int n_in,
                              void* d_out, int out_size, void* d_ws, size_t ws_size,
                              hipStream_t stream) {
    const int*   ei        = (const int*)d_in[0];
    const int*   ports     = (const int*)d_in[1];
    const int*   flags     = (const int*)d_in[2];
    const float* eattr     = (const float*)d_in[3];
    const int*   batch     = (const int*)d_in[4];
    const float* emb_port  = (const float*)d_in[5];
    const float* emb_flags = (const float*)d_in[6];
    const float* W1  = (const float*)d_in[7];
    const float* b1  = (const float*)d_in[8];
    const float* W2  = (const float*)d_in[9];
    const float* b2  = (const float*)d_in[10];
    const float* CW1 = (const float*)d_in[11];
    const float* Cb1 = (const float*)d_in[12];
    const float* CW2 = (const float*)d_in[13];
    const float* Cb2 = (const float*)d_in[14];
    float* outp = (float*)d_out;

    const int E = in_sizes[0] / 2;
    const int N = in_sizes[4];
    const int B = out_size / NCLS;
    const int NB = (N + 255) / 256;     // scan blocks (must be <= 512)

    // ---- workspace layout (~118 MB; proven-safe budget >= 142 MB) ----
    char* w = (char*)d_ws;
    float*    xA         = (float*)w;   w += (size_t)N * HID * 4;
    float*    xB         = (float*)w;   w += (size_t)N * HID * 4;
    float*    s          = (float*)w;   w += (size_t)N * HID * 4;   // fully written by node_mlp
    int*      eid_sorted = (int*)w;     w += (size_t)E * 4;
    int*      src_sorted = (int*)w;     w += (size_t)E * 4;
    int*      col_sorted = (int*)w;     w += (size_t)E * 4;
    unsigned* pf_sorted  = (unsigned*)w; w += (size_t)E * 4;
    int*      offs       = (int*)w;     w += (size_t)N * 4;
    int*      cursor     = (int*)w;     w += (size_t)N * 4;
    int*      loc        = (int*)w;     w += (size_t)N * 4;
    int*      part       = (int*)w;     w += 512 * 4;
    // zero region (single memset): hist, hsum, lsum, psum, pmax, pcnt
    char* zero_base = w;
    int*      hist  = (int*)w;          w += (size_t)N * 4;
    float*    hsum  = (float*)w;        w += (size_t)N * HID * 4;
    float*    lsum  = (float*)w;        w += (size_t)N * IN_DIM * 4;
    float*    psum  = (float*)w;        w += (size_t)B * HID * 4;
    unsigned* pmax  = (unsigned*)w;     w += (size_t)B * HID * 4;
    float*    pcnt  = (float*)w;        w += (size_t)B * 4;
    size_t zero_bytes = (size_t)(w - zero_base);

    hipMemsetAsync(zero_base, 0, zero_bytes, stream);

    // CSR build + bucket sort by col
    hist_pass<<<(E + 255) / 256, 256, 0, stream>>>(ei, hist, E);
    scan1<<<NB, 256, 0, stream>>>(hist, loc, part, N);
    scan2<<<1, 512, 0, stream>>>(part, NB);
    scan3<<<NB, 256, 0, stream>>>(loc, part, offs, cursor, N);
    sort_pass<<<(E + 255) / 256, 256, 0, stream>>>(
        ei, ports, flags, cursor, eid_sorted, src_sorted, col_sorted, pf_sorted, E);

    // edge hidden-layer + segmented reduction -> hsum, lsum
    edge_hidden_reduce<<<(E + BLK - 1) / BLK, BLK, 0, stream>>>(
        eid_sorted, col_sorted, pf_sorted, eattr, emb_port, emb_flags,
        W1, b1, hsum, lsum, E);

    // per-node: self-loop hidden + W2 -> s, x1
    node_mlp<<<(N + 255) / 256, 256, 0, stream>>>(
        lsum, hsum, hist, W1, b1, W2, b2, s, xA, N);

    // layers 2 and 3
    gather_layer<<<(N + 3) / 4, 256, 0, stream>>>(
        offs, hist, src_sorted, xA, s, xB, N);
    gather_layer<<<(N + 3) / 4, 256, 0, stream>>>(
        offs, hist, src_sorted, xB, s, xA, N);

    // pooling + classifier
    pool_pass<<<((N + 63) / 64 * 64 + 255) / 256, 256, 0, stream>>>(
        xA, batch, psum, pmax, pcnt, N);
    classifier_pass<<<B, 64, 0, stream>>>(psum, pmax, pcnt, CW1, Cb1, CW2, Cb2, outp);
}

// Round 10
// 871.780 us; speedup vs baseline: 1.5096x; 1.0916x over previous
//
#include <hip/hip_runtime.h>

#define HID 64
#define IN_DIM 34
#define NCLS 10
#define BLK 128
#define TSTR 35   // ea tile row stride (odd -> conflict-free col reads)
#define HSTR 17   // h tile row stride (odd)

// ---------- helpers ----------

__device__ __forceinline__ unsigned enc_f(float f) {
    unsigned u = __float_as_uint(f);
    return (u & 0x80000000u) ? ~u : (u | 0x80000000u);
}
__device__ __forceinline__ float dec_f(unsigned u) {
    return __uint_as_float((u & 0x80000000u) ? (u & 0x7FFFFFFFu) : ~u);
}

// ---------- CSR build ----------

__global__ __launch_bounds__(256) void hist_pass(
        const int* __restrict__ ei, int* __restrict__ hist, int E) {
    int e = blockIdx.x * blockDim.x + threadIdx.x;
    if (e >= E) return;
    atomicAdd(&hist[ei[E + e]], 1);
}

__global__ __launch_bounds__(256) void scan1(
        const int* __restrict__ hist, int* __restrict__ loc,
        int* __restrict__ part, int N) {
    __shared__ int sh[256];
    int tid = threadIdx.x;
    int i = blockIdx.x * 256 + tid;
    int v = (i < N) ? hist[i] : 0;
    sh[tid] = v;
    __syncthreads();
    for (int d = 1; d < 256; d <<= 1) {
        int t = (tid >= d) ? sh[tid - d] : 0;
        __syncthreads();
        sh[tid] += t;
        __syncthreads();
    }
    if (i < N) loc[i] = sh[tid] - v;          // exclusive
    if (tid == 255) part[blockIdx.x] = sh[255];
}

__global__ __launch_bounds__(512) void scan2(int* __restrict__ part, int NB) {
    __shared__ int sh[512];
    int t = threadIdx.x;
    int v = (t < NB) ? part[t] : 0;
    sh[t] = v;
    __syncthreads();
    for (int d = 1; d < 512; d <<= 1) {
        int u = (t >= d) ? sh[t - d] : 0;
        __syncthreads();
        sh[t] += u;
        __syncthreads();
    }
    if (t < NB) part[t] = sh[t] - v;          // exclusive
}

__global__ __launch_bounds__(256) void scan3(
        const int* __restrict__ loc, const int* __restrict__ part,
        int* __restrict__ offs, int* __restrict__ cursor, int N) {
    int i = blockIdx.x * 256 + threadIdx.x;
    if (i >= N) return;
    int o = loc[i] + part[blockIdx.x];
    offs[i] = o;
    cursor[i] = o;
}

// bucket edges by col into ONE packed record (1 scattered line per edge,
// not 4): rec = {eid, src, col, port|flag<<16}
__global__ __launch_bounds__(256) void sort_pass(
        const int* __restrict__ ei, const int* __restrict__ ports,
        const int* __restrict__ flags, int* __restrict__ cursor,
        int4* __restrict__ rec, int E) {
    int e = blockIdx.x * blockDim.x + threadIdx.x;
    if (e >= E) return;
    int c = ei[E + e];
    int pos = atomicAdd(&cursor[c], 1);
    int4 r;
    r.x = e;
    r.y = ei[e];
    r.z = c;
    r.w = (int)((unsigned)ports[e] | ((unsigned)flags[e] << 16));
    rec[pos] = r;
}

// ---------- edge hidden-layer + block segmented reduction ----------
// s[n] = (sum_e relu(ea_e W1 + b1) + h_loop) W2 + (d+1) b2 -- this kernel
// produces hsum = sum_e relu(...) and lsum = sum_e ea.
// REGISTER DISCIPLINE (R4-R9 lessons): NO array is live across any barrier.
// ea is staged to LDS once (regs die at the store+sync; the sync is a shared
// fence so the compiler cannot forward the stored values); the hidden layer
// is computed in four 16-col quarters reading ea back from LDS elementwise,
// each h[16] transient. LDS = 128*35 + 128*17 + 128 ints = 27.1 KB ->
// 6 blocks/CU = 12 waves/CU.
__global__ __launch_bounds__(BLK) void edge_hidden_reduce(
        const int4* __restrict__ rec, const float* __restrict__ eattr,
        const float* __restrict__ emb_port, const float* __restrict__ emb_flags,
        const float* __restrict__ W1, const float* __restrict__ b1,
        float* __restrict__ hsum, float* __restrict__ lsum, int E) {
    __shared__ float ea_t[BLK * TSTR];
    __shared__ float h_t[BLK * HSTR];
    __shared__ int col_sh[BLK];

    int tid = threadIdx.x;
    int lane = tid & 63;
    int wv = tid >> 6;
    int idx = blockIdx.x * BLK + tid;
    bool valid = idx < E;

    // ---- gather ea[34] (transient regs) and stage to LDS ----
    {
        float ea[IN_DIM];
        #pragma unroll
        for (int k = 0; k < IN_DIM; ++k) ea[k] = 0.0f;
        int colv = -1;
        if (valid) {
            int4 r = rec[idx];
            colv = r.z;
            int eid = r.x;
            const float4* ap = (const float4*)(eattr + (size_t)eid * 16);
            float4 a0 = ap[0], a1 = ap[1], a2 = ap[2], a3 = ap[3];
            ea[0]=a0.x; ea[1]=a0.y; ea[2]=a0.z; ea[3]=a0.w;
            ea[4]=a1.x; ea[5]=a1.y; ea[6]=a1.z; ea[7]=a1.w;
            ea[8]=a2.x; ea[9]=a2.y; ea[10]=a2.z; ea[11]=a2.w;
            ea[12]=a3.x; ea[13]=a3.y; ea[14]=a3.z; ea[15]=a3.w;
            unsigned pf = (unsigned)r.w;
            int p = (int)(pf & 0xFFFFu);
            int f = (int)(pf >> 16);
            const float4* pp = (const float4*)(emb_port + (size_t)p * 16);
            float4 p0 = pp[0], p1 = pp[1], p2 = pp[2], p3 = pp[3];
            ea[16]=p0.x; ea[17]=p0.y; ea[18]=p0.z; ea[19]=p0.w;
            ea[20]=p1.x; ea[21]=p1.y; ea[22]=p1.z; ea[23]=p1.w;
            ea[24]=p2.x; ea[25]=p2.y; ea[26]=p2.z; ea[27]=p2.w;
            ea[28]=p3.x; ea[29]=p3.y; ea[30]=p3.z; ea[31]=p3.w;
            float2 fl = *(const float2*)(emb_flags + (size_t)f * 2);
            ea[32]=fl.x; ea[33]=fl.y;
        }
        col_sh[tid] = colv;
        #pragma unroll
        for (int k = 0; k < IN_DIM; ++k) ea_t[tid * TSTR + k] = ea[k];
    }
    __syncthreads();   // ea + col_sh visible; ea regs dead past this fence

    // ---- phase 1: lsum reduce (64-row strip per wave, lane<34 = channel) ----
    {
        int cj = (lane < IN_DIM) ? lane : IN_DIM;   // col 34 = in-stride dummy
        int r0 = wv * 64;
        float acc = 0.0f;
        int cur = col_sh[r0];
        #pragma unroll 1
        for (int rb = 0; rb < 64; rb += 8) {
            float v[8];
            #pragma unroll
            for (int u = 0; u < 8; ++u)
                v[u] = ea_t[(r0 + rb + u) * TSTR + cj];
            #pragma unroll
            for (int u = 0; u < 8; ++u) {
                int cr = col_sh[r0 + rb + u];
                if (cr != cur) {
                    if (cur >= 0 && lane < IN_DIM)
                        atomicAdd(&lsum[(size_t)cur * IN_DIM + lane], acc);
                    acc = 0.0f;
                    cur = cr;
                }
                acc += v[u];
            }
        }
        if (cur >= 0 && lane < IN_DIM)
            atomicAdd(&lsum[(size_t)cur * IN_DIM + lane], acc);
    }
    // no barrier needed: nothing below writes ea_t, h_t is a separate region

    // ---- quarters: h[16] = relu(ea @ W1[:, q*16:+16] + b1), reduce -> hsum ----
    #pragma unroll 1
    for (int q = 0; q < 4; ++q) {
        int cbase = q * 16;
        float h[16];
        #pragma unroll
        for (int j = 0; j < 16; ++j) h[j] = b1[cbase + j];
        #pragma unroll 2
        for (int k = 0; k < IN_DIM; ++k) {
            float v = ea_t[tid * TSTR + k];   // own row: no cross-thread hazard
            #pragma unroll
            for (int j = 0; j < 16; ++j)
                h[j] = fmaf(v, W1[k * HID + cbase + j], h[j]);
        }
        #pragma unroll
        for (int j = 0; j < 16; ++j)
            h_t[tid * HSTR + j] = fmaxf(h[j], 0.0f);   // h dies here
        __syncthreads();

        // reduce: 4 strips of 16 rows per wave; lane&15 owns one column
        int colL = lane & 15;
        int r0 = wv * 64 + (lane >> 4) * 16;
        float acc = 0.0f;
        int cur = col_sh[r0];
        #pragma unroll 1
        for (int rb = 0; rb < 16; rb += 8) {
            float v[8];
            #pragma unroll
            for (int u = 0; u < 8; ++u)
                v[u] = h_t[(r0 + rb + u) * HSTR + colL];
            #pragma unroll
            for (int u = 0; u < 8; ++u) {
                int cr = col_sh[r0 + rb + u];
                if (cr != cur) {
                    if (cur >= 0)
                        atomicAdd(&hsum[(size_t)cur * HID + cbase + colL], acc);
                    acc = 0.0f;
                    cur = cr;
                }
                acc += v[u];
            }
        }
        if (cur >= 0)
            atomicAdd(&hsum[(size_t)cur * HID + cbase + colL], acc);
        __syncthreads();
    }
}

// Thread per node: self-loop hidden, add hsum, apply W2 once per node.
// s[n] = (hsum[n] + relu(lsum/c W1 + b1)) W2 + (d+1) b2 ; x1 = s / (d+1)
__global__ __launch_bounds__(256) void node_mlp(
        const float* __restrict__ lsum, const float* __restrict__ hsum,
        const int* __restrict__ hist,
        const float* __restrict__ W1, const float* __restrict__ b1,
        const float* __restrict__ W2, const float* __restrict__ b2,
        float* __restrict__ s, float* __restrict__ x1, int N) {
    int n = blockIdx.x * blockDim.x + threadIdx.x;
    if (n >= N) return;
    int c = hist[n];
    float invc = 1.0f / fmaxf((float)c, 1.0f);

    float hs[HID];
    #pragma unroll
    for (int j = 0; j < HID; ++j) hs[j] = b1[j];
    #pragma unroll 1
    for (int k = 0; k < IN_DIM; ++k) {
        float v = lsum[(size_t)n * IN_DIM + k] * invc;
        #pragma unroll
        for (int j = 0; j < HID; ++j)
            hs[j] = fmaf(v, W1[k * HID + j], hs[j]);
    }
    const float* hp = hsum + (size_t)n * HID;
    #pragma unroll
    for (int j = 0; j < HID; ++j) hs[j] = fmaxf(hs[j], 0.0f) + hp[j];

    float degf = (float)(c + 1);
    float invdeg = 1.0f / degf;
    float* sp = s + (size_t)n * HID;
    float* xp = x1 + (size_t)n * HID;
    #pragma unroll 1
    for (int jb = 0; jb < HID; jb += 8) {
        float o[8];
        #pragma unroll
        for (int u = 0; u < 8; ++u) o[u] = degf * b2[jb + u];
        #pragma unroll 2
        for (int k = 0; k < HID; ++k) {
            float hv = hs[k];
            #pragma unroll
            for (int u = 0; u < 8; ++u)
                o[u] = fmaf(hv, W2[k * HID + jb + u], o[u]);
        }
        #pragma unroll
        for (int u = 0; u < 8; ++u) {
            sp[jb + u] = o[u];
            xp[jb + u] = o[u] * invdeg;
        }
    }
}

// Wave per node, 8-wide pipelined gather; src comes from the packed rec.
// xn[n] = (sum_{incoming} x[src] + x[n] + s[n]) / deg
__global__ __launch_bounds__(256) void gather_layer(
        const int* __restrict__ offs, const int* __restrict__ hist,
        const int4* __restrict__ rec, const float* __restrict__ x,
        const float* __restrict__ s, float* __restrict__ xn, int N) {
    int wid = (blockIdx.x * blockDim.x + threadIdx.x) >> 6;
    int lane = threadIdx.x & 63;
    if (wid >= N) return;
    int off = offs[wid], d = hist[wid];
    float acc = x[(size_t)wid * HID + lane] + s[(size_t)wid * HID + lane];
    int i = 0;
    for (; i + 8 <= d; i += 8) {
        int r[8];
        #pragma unroll
        for (int u = 0; u < 8; ++u) r[u] = rec[off + i + u].y;
        float v[8];
        #pragma unroll
        for (int u = 0; u < 8; ++u) v[u] = x[(size_t)r[u] * HID + lane];
        #pragma unroll
        for (int u = 0; u < 8; ++u) acc += v[u];
    }
    for (; i < d; ++i) {
        int r = rec[off + i].y;
        acc += x[(size_t)r * HID + lane];
    }
    xn[(size_t)wid * HID + lane] = acc / (float)(d + 1);
}

// Wave per 64-node chunk; batch[] is sorted so flushes are rare.
__global__ __launch_bounds__(256) void pool_pass(
        const float* __restrict__ x, const int* __restrict__ batch,
        float* __restrict__ psum, unsigned* __restrict__ pmax,
        float* __restrict__ pcnt, int N) {
    const int CHUNK = 64;
    int wid = (blockIdx.x * blockDim.x + threadIdx.x) >> 6;
    int lane = threadIdx.x & 63;
    int n0 = wid * CHUNK;
    if (n0 >= N) return;
    int n1 = min(n0 + CHUNK, N);
    int gcur = batch[n0];
    float sum = 0.0f, mx = -3.402823e38f;
    int cnt = 0;
    for (int n = n0; n < n1; ++n) {
        int g = batch[n];
        if (g != gcur) {
            atomicAdd(&psum[gcur * HID + lane], sum);
            atomicMax(&pmax[gcur * HID + lane], enc_f(mx));
            if (lane == 0) atomicAdd(&pcnt[gcur], (float)cnt);
            gcur = g; sum = 0.0f; mx = -3.402823e38f; cnt = 0;
        }
        float v = x[(size_t)n * HID + lane];
        sum += v;
        mx = fmaxf(mx, v);
        ++cnt;
    }
    atomicAdd(&psum[gcur * HID + lane], sum);
    atomicMax(&pmax[gcur * HID + lane], enc_f(mx));
    if (lane == 0) atomicAdd(&pcnt[gcur], (float)cnt);
}

__global__ __launch_bounds__(64) void classifier_pass(
        const float* __restrict__ psum, const unsigned* __restrict__ pmax,
        const float* __restrict__ pcnt,
        const float* __restrict__ CW1, const float* __restrict__ Cb1,
        const float* __restrict__ CW2, const float* __restrict__ Cb2,
        float* __restrict__ out) {
    int g = blockIdx.x, j = threadIdx.x;
    __shared__ float pooled[2 * HID];
    __shared__ float hsh[HID];
    float gc = fmaxf(pcnt[g], 1.0f);
    pooled[j] = psum[g * HID + j] / gc;
    pooled[HID + j] = dec_f(pmax[g * HID + j]);
    __syncthreads();
    float acc = Cb1[j];
    #pragma unroll 8
    for (int k = 0; k < 2 * HID; ++k) acc = fmaf(pooled[k], CW1[k * HID + j], acc);
    hsh[j] = fmaxf(acc, 0.0f);
    __syncthreads();
    if (j < NCLS) {
        float o = Cb2[j];
        #pragma unroll 8
        for (int k = 0; k < HID; ++k) o = fmaf(hsh[k], CW2[k * NCLS + j], o);
        out[g * NCLS + j] = o;
    }
}

// ---------- launch ----------

extern "C" void kernel_launch(void* const* d_in, const int* in_sizes, int n_in,
                              void* d_out, int out_size, void* d_ws, size_t ws_size,
                              hipStream_t stream) {
    const int*   ei        = (const int*)d_in[0];
    const int*   ports     = (const int*)d_in[1];
    const int*   flags     = (const int*)d_in[2];
    const float* eattr     = (const float*)d_in[3];
    const int*   batch     = (const int*)d_in[4];
    const float* emb_port  = (const float*)d_in[5];
    const float* emb_flags = (const float*)d_in[6];
    const float* W1  = (const float*)d_in[7];
    const float* b1  = (const float*)d_in[8];
    const float* W2  = (const float*)d_in[9];
    const float* b2  = (const float*)d_in[10];
    const float* CW1 = (const float*)d_in[11];
    const float* Cb1 = (const float*)d_in[12];
    const float* CW2 = (const float*)d_in[13];
    const float* Cb2 = (const float*)d_in[14];
    float* outp = (float*)d_out;

    const int E = in_sizes[0] / 2;
    const int N = in_sizes[4];
    const int B = out_size / NCLS;
    const int NB = (N + 255) / 256;     // scan blocks (must be <= 512)

    // ---- workspace layout (~118 MB; proven-safe budget >= 142 MB) ----
    char* w = (char*)d_ws;
    float*    xA   = (float*)w;   w += (size_t)N * HID * 4;
    float*    xB   = (float*)w;   w += (size_t)N * HID * 4;
    float*    s    = (float*)w;   w += (size_t)N * HID * 4;
    int4*     rec  = (int4*)w;    w += (size_t)E * 16;     // packed sorted records
    int*      offs = (int*)w;     w += (size_t)N * 4;
    int*      cursor = (int*)w;   w += (size_t)N * 4;
    int*      loc  = (int*)w;     w += (size_t)N * 4;
    int*      part = (int*)w;     w += 512 * 4;
    // zero region (single memset): hist, hsum, lsum, psum, pmax, pcnt
    char* zero_base = w;
    int*      hist = (int*)w;     w += (size_t)N * 4;
    float*    hsum = (float*)w;   w += (size_t)N * HID * 4;
    float*    lsum = (float*)w;   w += (size_t)N * IN_DIM * 4;
    float*    psum = (float*)w;   w += (size_t)B * HID * 4;
    unsigned* pmax = (unsigned*)w; w += (size_t)B * HID * 4;
    float*    pcnt = (float*)w;   w += (size_t)B * 4;
    size_t zero_bytes = (size_t)(w - zero_base);

    hipMemsetAsync(zero_base, 0, zero_bytes, stream);

    // CSR build + bucket sort by col (packed record)
    hist_pass<<<(E + 255) / 256, 256, 0, stream>>>(ei, hist, E);
    scan1<<<NB, 256, 0, stream>>>(hist, loc, part, N);
    scan2<<<1, 512, 0, stream>>>(part, NB);
    scan3<<<NB, 256, 0, stream>>>(loc, part, offs, cursor, N);
    sort_pass<<<(E + 255) / 256, 256, 0, stream>>>(
        ei, ports, flags, cursor, rec, E);

    // edge hidden-layer + segmented reduction -> hsum, lsum
    edge_hidden_reduce<<<(E + BLK - 1) / BLK, BLK, 0, stream>>>(
        rec, eattr, emb_port, emb_flags, W1, b1, hsum, lsum, E);

    // per-node: self-loop hidden + W2 -> s, x1
    node_mlp<<<(N + 255) / 256, 256, 0, stream>>>(
        lsum, hsum, hist, W1, b1, W2, b2, s, xA, N);

    // layers 2 and 3
    gather_layer<<<(N + 3) / 4, 256, 0, stream>>>(
        offs, hist, rec, xA, s, xB, N);
    gather_layer<<<(N + 3) / 4, 256, 0, stream>>>(
        offs, hist, rec, xB, s, xA, N);

    // pooling + classifier
    pool_pass<<<((N + 63) / 64 * 64 + 255) / 256, 256, 0, stream>>>(
        xA, batch, psum, pmax, pcnt, N);
    classifier_pass<<<B, 64, 0, stream>>>(psum, pmax, pcnt, CW1, Cb1, CW2, Cb2, outp);
}